// Round 4
// baseline (277.208 us; speedup 1.0000x reference)
//
#include <hip/hip_runtime.h>

// Shapes: B=1, N=4096, C=256, H=8, d=32.
// ws layout (ushort elems):
//   Q[2][8][4096][32]          @ 0         (Q pre-scaled by d^-0.5*log2e)
//   K[2][8][4096][32]          @ KOFF
//   Vt[2][8][32][4096]         @ VOFF      (key dim permuted per 128-block:
//                                           k' = (k&15)*8 + (k>>4))
//   WBF[24][8192]              @ WOFF      (W bf16, swizzled to B-frag order)

typedef __attribute__((ext_vector_type(8))) short short8;
typedef __attribute__((ext_vector_type(4))) float float4v;
typedef __attribute__((ext_vector_type(4))) unsigned int uint4v;

#define NTOK 4096
#define CDIM 256
#define HEADS 8
#define DHEAD 32

#define QOFF 0
#define KOFF (2*HEADS*NTOK*DHEAD)
#define VOFF (2*(2*HEADS*NTOK*DHEAD))
#define WOFF (3*(2*HEADS*NTOK*DHEAD))

__device__ inline unsigned short f2bf(float f) {
    union { float f; unsigned u; } v; v.f = f;
    unsigned r = v.u + 0x7FFFu + ((v.u >> 16) & 1u);   // RNE
    return (unsigned short)(r >> 16);
}

// ---------------------------------------------------------------------------
// Kernel 0: W fp32 -> bf16, swizzled so a B-fragment is one contiguous 16B
// load: WBF[o32*8192 + (kk*2+nhalf)*512 + (quad*16+l16)*8 + j]
//   = bf16( W[o32*32 + nhalf*16 + l16][kk*32 + quad*8 + j] )
// ---------------------------------------------------------------------------
__global__ __launch_bounds__(256) void wconv_kernel(
    const float* __restrict__ W, unsigned short* __restrict__ ws)
{
    int idx = blockIdx.x*256 + threadIdx.x;    // [0, 24576): (row, col-octet)
    int R = idx >> 5, oct = idx & 31;
    int C = oct * 8;
    const float4* p = reinterpret_cast<const float4*>(W + R*CDIM + C);
    float4 a = p[0], b = p[1];
    short8 f;
    f[0]=(short)f2bf(a.x); f[1]=(short)f2bf(a.y); f[2]=(short)f2bf(a.z); f[3]=(short)f2bf(a.w);
    f[4]=(short)f2bf(b.x); f[5]=(short)f2bf(b.y); f[6]=(short)f2bf(b.z); f[7]=(short)f2bf(b.w);
    int o32 = R >> 5, r = R & 31;
    int kk = C >> 5, quad = (C >> 3) & 3;
    int dst = o32*8192 + (kk*2 + (r>>4))*512 + (quad*16 + (r&15))*8;
    *reinterpret_cast<short8*>(ws + WOFF + dst) = f;
}

// ---------------------------------------------------------------------------
// Kernel 1: t = x @ W^T (bf16 MFMA) + LayerNorm over d=32 groups.
// No LDS, no barriers: B-frags are direct 16B coalesced loads from WBF.
// grid = 512: (row-tile 0..127) x (o-quarter 0..3, 6 o32-groups each).
// ---------------------------------------------------------------------------
__global__ __launch_bounds__(256) void qkv_ln_kernel(
    const float* __restrict__ before, const float* __restrict__ after,
    const float* __restrict__ gamma, const float* __restrict__ beta,
    unsigned short* __restrict__ ws)
{
    const int tid  = threadIdx.x;
    const int lane = tid & 63;
    const int w    = tid >> 6;
    const int quad = lane >> 4;
    const int l16  = lane & 15;
    const int rt   = blockIdx.x >> 2;
    const int oq   = blockIdx.x & 3;

    // A-fragment rows (m = l16)
    const int mrow_frag = rt*64 + w*16 + l16;
    const int inp_f = mrow_frag >> 12;
    const int n_f   = mrow_frag & 4095;
    const float* x = inp_f ? after : before;

    short8 afrag[8];
#pragma unroll
    for (int kk = 0; kk < 8; kk++) {
        const float4* p = reinterpret_cast<const float4*>(x + n_f*CDIM + kk*32 + quad*8);
        float4 a = p[0], b = p[1];
        short8 f;
        f[0]=(short)f2bf(a.x); f[1]=(short)f2bf(a.y); f[2]=(short)f2bf(a.z); f[3]=(short)f2bf(a.w);
        f[4]=(short)f2bf(b.x); f[5]=(short)f2bf(b.y); f[6]=(short)f2bf(b.z); f[7]=(short)f2bf(b.w);
        afrag[kk] = f;
    }

    const float g0  = gamma[l16], g1  = gamma[16+l16];
    const float be0 = beta[l16],  be1 = beta[16+l16];
    const float cscale = 0.17677669529663687f * 1.4426950408889634f; // d^-0.5*log2e

    // C/D rows for this wave: quad*4 + i
    const int mrow_out  = rt*64 + w*16 + quad*4;
    const int inp_o     = mrow_out >> 12;
    const int n_o_base  = mrow_out & 4095;

    const unsigned short* wbf = ws + WOFF;

    for (int o32 = oq*6; o32 < oq*6 + 6; o32++) {
        const unsigned short* wb = wbf + o32*8192 + lane*8;
        float4v acc0 = {0.f,0.f,0.f,0.f}, acc1 = {0.f,0.f,0.f,0.f};
#pragma unroll
        for (int kk = 0; kk < 8; kk++) {
            short8 b0 = *reinterpret_cast<const short8*>(wb + (kk*2    )*512);
            short8 b1 = *reinterpret_cast<const short8*>(wb + (kk*2 + 1)*512);
            acc0 = __builtin_amdgcn_mfma_f32_16x16x32_bf16(afrag[kk], b0, acc0, 0,0,0);
            acc1 = __builtin_amdgcn_mfma_f32_16x16x32_bf16(afrag[kk], b1, acc1, 0,0,0);
        }

        const int which = o32 >> 3;     // 0=q 1=k 2=v
        const int h     = o32 & 7;
        unsigned short* qk = ws + (which == 0 ? QOFF : KOFF) + ((inp_o*HEADS + h)*NTOK)*DHEAD;
        unsigned short* vt = ws + VOFF + ((inp_o*HEADS + h)*DHEAD)*NTOK;
        const float qs = (which == 0) ? cscale : 1.0f;

#pragma unroll
        for (int i = 0; i < 4; i++) {
            float sum = acc0[i] + acc1[i];
            float sq  = acc0[i]*acc0[i] + acc1[i]*acc1[i];
#pragma unroll
            for (int m = 1; m < 16; m <<= 1) {
                sum += __shfl_xor(sum, m);
                sq  += __shfl_xor(sq,  m);
            }
            float mu   = sum * (1.0f/32.0f);
            float var  = sq * (1.0f/32.0f) - mu*mu;
            float rstd = rsqrtf(var + 1e-5f);
            float v0 = ((acc0[i]-mu)*rstd*g0 + be0) * qs;
            float v1 = ((acc1[i]-mu)*rstd*g1 + be1) * qs;
            int n = n_o_base + i;
            if (which < 2) {
                qk[n*DHEAD + l16]      = f2bf(v0);
                qk[n*DHEAD + 16 + l16] = f2bf(v1);
            } else {
                int kb = n >> 7, ki = n & 127;
                int kp = kb*128 + (ki & 15)*8 + (ki >> 4);
                vt[l16*NTOK + kp]       = f2bf(v0);
                vt[(16+l16)*NTOK + kp]  = f2bf(v1);
            }
        }
    }
}

// ---------------------------------------------------------------------------
// Kernel 2: cross attention, max-free softmax, raw v_exp_f32.
// Barrier-free: K and V fragments read directly from global (L1/L2-resident,
// identical addresses across the block's 4 waves); P round-trips through a
// per-wave LDS region (same-wave DS ordering only). Wave owns 16 q-rows;
// grid (64,8,2) = 1024 blocks = 4 blocks/CU, LDS 17.4 KB.
// ---------------------------------------------------------------------------
__global__ __launch_bounds__(256, 4) void attn_kernel(
    const unsigned short* __restrict__ ws, float* __restrict__ out)
{
    __shared__ unsigned short plds[4*16*136];   // per-wave 16 q x 128 k'

    const int X  = blockIdx.z;
    const int h  = blockIdx.y;
    const int qb = blockIdx.x;                  // 64 q-rows per block
    const int qinp = 1 - X, kvinp = X;
    const int tid  = threadIdx.x;
    const int lane = tid & 63;
    const int w    = tid >> 6;
    const int quad = lane >> 4;
    const int l16  = lane & 15;

    const unsigned short* qbase = ws + QOFF + ((qinp*HEADS + h)*NTOK)*DHEAD;
    const unsigned short* kbase = ws + KOFF + ((kvinp*HEADS + h)*NTOK)*DHEAD;
    const unsigned short* vbase = ws + VOFF + ((kvinp*HEADS + h)*DHEAD)*NTOK;

    const int q0 = qb*64 + w*16;
    const short8 qf = *reinterpret_cast<const short8*>(qbase + (q0 + l16)*DHEAD + quad*8);

    // V B-fragment bases: Vt[half*16+l16][kt*128 + kk*32 + quad*8 .. +7]
    const unsigned short* vp0 = vbase + l16*NTOK      + quad*8;
    const unsigned short* vp1 = vbase + (16+l16)*NTOK + quad*8;
    const unsigned short* kp  = kbase + (l16)*32 + quad*8;

    float4v O0 = {0,0,0,0}, O1 = {0,0,0,0};
    float rs[4] = {0.f,0.f,0.f,0.f};

    unsigned short* pw = plds + w*(16*136);

    for (int kt = 0; kt < 32; kt++) {
        // S = Q K^T : K-fragments straight from global
        float4v S[8];
#pragma unroll
        for (int t = 0; t < 8; t++) {
            short8 kf = *reinterpret_cast<const short8*>(kp + (kt*128 + t*16)*32);
            float4v z = {0,0,0,0};
            S[t] = __builtin_amdgcn_mfma_f32_16x16x32_bf16(qf, kf, z, 0,0,0);
        }

        // p = exp2(S); pack pairs -> one b128 write per row group (per-wave
        // LDS region: same-wave ordering, no barrier).
#pragma unroll
        for (int i = 0; i < 4; i++) {
            uint4v wv;
#pragma unroll
            for (int j = 0; j < 4; j++) {
                float pa = __builtin_amdgcn_exp2f(S[2*j][i]);
                float pb = __builtin_amdgcn_exp2f(S[2*j+1][i]);
                rs[i] += pa + pb;
                union { float f; unsigned u; } ua, ub;
                ua.f = pa; ub.f = pb;
                wv[j] = __builtin_amdgcn_perm(ub.u + 0x8000u, ua.u + 0x8000u,
                                              0x07060302u);
            }
            *reinterpret_cast<uint4v*>(pw + (quad*4 + i)*136 + l16*8) = wv;
        }

        // O += P V : P A-frags from per-wave LDS, V B-frags from global
#pragma unroll
        for (int kk = 0; kk < 4; kk++) {
            short8 p  = *reinterpret_cast<const short8*>(pw + l16*136 + kk*32 + quad*8);
            short8 v0 = *reinterpret_cast<const short8*>(vp0 + kt*128 + kk*32);
            short8 v1 = *reinterpret_cast<const short8*>(vp1 + kt*128 + kk*32);
            O0 = __builtin_amdgcn_mfma_f32_16x16x32_bf16(p, v0, O0, 0,0,0);
            O1 = __builtin_amdgcn_mfma_f32_16x16x32_bf16(p, v1, O1, 0,0,0);
        }
    }

    float* ob = out + (size_t)X*NTOK*CDIM + h*DHEAD;
#pragma unroll
    for (int i = 0; i < 4; i++) {
        float l = rs[i];
#pragma unroll
        for (int m = 1; m < 16; m <<= 1) l += __shfl_xor(l, m);
        int row = q0 + quad*4 + i;
        float inv = 1.0f / l;
        ob[row*CDIM + l16]      = O0[i] * inv;
        ob[row*CDIM + 16 + l16] = O1[i] * inv;
    }
}

extern "C" void kernel_launch(void* const* d_in, const int* in_sizes, int n_in,
                              void* d_out, int out_size, void* d_ws, size_t ws_size,
                              hipStream_t stream)
{
    const float* before = (const float*)d_in[0];
    const float* after  = (const float*)d_in[1];
    const float* W      = (const float*)d_in[2];
    const float* gamma  = (const float*)d_in[3];
    const float* beta   = (const float*)d_in[4];
    float* out          = (float*)d_out;
    unsigned short* ws  = (unsigned short*)d_ws;   // needs ~13.0 MB

    hipLaunchKernelGGL(wconv_kernel, dim3(96), dim3(256), 0, stream, W, ws);
    hipLaunchKernelGGL(qkv_ln_kernel, dim3(512), dim3(256), 0, stream,
                       before, after, gamma, beta, ws);
    hipLaunchKernelGGL(attn_kernel, dim3(64, 8, 2), dim3(256), 0, stream, ws, out);
}

// Round 5
// 226.051 us; speedup vs baseline: 1.2263x; 1.2263x over previous
//
#include <hip/hip_runtime.h>

// Shapes: B=1, N=4096, C=256, H=8, d=32.
// ws layout (ushort elems):
//   Q[2][8][4096][32]          @ 0         (Q pre-scaled by d^-0.5*log2e)
//   K[2][8][4096][32]          @ KOFF
//   Vt[2][8][32][4096]         @ VOFF      (key dim permuted per 128-block:
//                                           k' = (k&15)*8 + (k>>4))
//   WBF[24][8192]              @ WOFF      (W bf16, swizzled to B-frag order)

typedef __attribute__((ext_vector_type(8))) short short8;
typedef __attribute__((ext_vector_type(4))) float float4v;
typedef __attribute__((ext_vector_type(4))) unsigned int uint4v;

#define NTOK 4096
#define CDIM 256
#define HEADS 8
#define DHEAD 32

#define QOFF 0
#define KOFF (2*HEADS*NTOK*DHEAD)
#define VOFF (2*(2*HEADS*NTOK*DHEAD))
#define WOFF (3*(2*HEADS*NTOK*DHEAD))

__device__ inline unsigned short f2bf(float f) {
    union { float f; unsigned u; } v; v.f = f;
    unsigned r = v.u + 0x7FFFu + ((v.u >> 16) & 1u);   // RNE
    return (unsigned short)(r >> 16);
}

// ---------------------------------------------------------------------------
// Kernel 0: W fp32 -> bf16, swizzled so a B-fragment is one contiguous 16B
// load: WBF[o32*8192 + (kk*2+nhalf)*512 + (quad*16+l16)*8 + j]
// ---------------------------------------------------------------------------
__global__ __launch_bounds__(256) void wconv_kernel(
    const float* __restrict__ W, unsigned short* __restrict__ ws)
{
    int idx = blockIdx.x*256 + threadIdx.x;    // [0, 24576): (row, col-octet)
    int R = idx >> 5, oct = idx & 31;
    int C = oct * 8;
    const float4* p = reinterpret_cast<const float4*>(W + R*CDIM + C);
    float4 a = p[0], b = p[1];
    short8 f;
    f[0]=(short)f2bf(a.x); f[1]=(short)f2bf(a.y); f[2]=(short)f2bf(a.z); f[3]=(short)f2bf(a.w);
    f[4]=(short)f2bf(b.x); f[5]=(short)f2bf(b.y); f[6]=(short)f2bf(b.z); f[7]=(short)f2bf(b.w);
    int o32 = R >> 5, r = R & 31;
    int kk = C >> 5, quad = (C >> 3) & 3;
    int dst = o32*8192 + (kk*2 + (r>>4))*512 + (quad*16 + (r&15))*8;
    *reinterpret_cast<short8*>(ws + WOFF + dst) = f;
}

// ---------------------------------------------------------------------------
// Kernel 1: t = x @ W^T (bf16 MFMA) + LayerNorm over d=32 groups.
// No LDS/barriers. grid = 1024: (row-tile 0..127) x (o-eighth 0..7, 3 o32s).
// ---------------------------------------------------------------------------
__global__ __launch_bounds__(256) void qkv_ln_kernel(
    const float* __restrict__ before, const float* __restrict__ after,
    const float* __restrict__ gamma, const float* __restrict__ beta,
    unsigned short* __restrict__ ws)
{
    const int tid  = threadIdx.x;
    const int lane = tid & 63;
    const int w    = tid >> 6;
    const int quad = lane >> 4;
    const int l16  = lane & 15;
    const int rt   = blockIdx.x >> 3;
    const int oq   = blockIdx.x & 7;

    const int mrow_frag = rt*64 + w*16 + l16;
    const int inp_f = mrow_frag >> 12;
    const int n_f   = mrow_frag & 4095;
    const float* x = inp_f ? after : before;

    short8 afrag[8];
#pragma unroll
    for (int kk = 0; kk < 8; kk++) {
        const float4* p = reinterpret_cast<const float4*>(x + n_f*CDIM + kk*32 + quad*8);
        float4 a = p[0], b = p[1];
        short8 f;
        f[0]=(short)f2bf(a.x); f[1]=(short)f2bf(a.y); f[2]=(short)f2bf(a.z); f[3]=(short)f2bf(a.w);
        f[4]=(short)f2bf(b.x); f[5]=(short)f2bf(b.y); f[6]=(short)f2bf(b.z); f[7]=(short)f2bf(b.w);
        afrag[kk] = f;
    }

    const float g0  = gamma[l16], g1  = gamma[16+l16];
    const float be0 = beta[l16],  be1 = beta[16+l16];
    const float cscale = 0.17677669529663687f * 1.4426950408889634f; // d^-0.5*log2e

    const int mrow_out  = rt*64 + w*16 + quad*4;
    const int inp_o     = mrow_out >> 12;
    const int n_o_base  = mrow_out & 4095;

    const unsigned short* wbf = ws + WOFF;

    for (int o32 = oq*3; o32 < oq*3 + 3; o32++) {
        const unsigned short* wb = wbf + o32*8192 + lane*8;
        float4v acc0 = {0.f,0.f,0.f,0.f}, acc1 = {0.f,0.f,0.f,0.f};
#pragma unroll
        for (int kk = 0; kk < 8; kk++) {
            short8 b0 = *reinterpret_cast<const short8*>(wb + (kk*2    )*512);
            short8 b1 = *reinterpret_cast<const short8*>(wb + (kk*2 + 1)*512);
            acc0 = __builtin_amdgcn_mfma_f32_16x16x32_bf16(afrag[kk], b0, acc0, 0,0,0);
            acc1 = __builtin_amdgcn_mfma_f32_16x16x32_bf16(afrag[kk], b1, acc1, 0,0,0);
        }

        const int which = o32 >> 3;     // 0=q 1=k 2=v
        const int h     = o32 & 7;
        unsigned short* qk = ws + (which == 0 ? QOFF : KOFF) + ((inp_o*HEADS + h)*NTOK)*DHEAD;
        unsigned short* vt = ws + VOFF + ((inp_o*HEADS + h)*DHEAD)*NTOK;
        const float qs = (which == 0) ? cscale : 1.0f;

#pragma unroll
        for (int i = 0; i < 4; i++) {
            float sum = acc0[i] + acc1[i];
            float sq  = acc0[i]*acc0[i] + acc1[i]*acc1[i];
#pragma unroll
            for (int m = 1; m < 16; m <<= 1) {
                sum += __shfl_xor(sum, m);
                sq  += __shfl_xor(sq,  m);
            }
            float mu   = sum * (1.0f/32.0f);
            float var  = sq * (1.0f/32.0f) - mu*mu;
            float rstd = rsqrtf(var + 1e-5f);
            float v0 = ((acc0[i]-mu)*rstd*g0 + be0) * qs;
            float v1 = ((acc1[i]-mu)*rstd*g1 + be1) * qs;
            int n = n_o_base + i;
            if (which < 2) {
                qk[n*DHEAD + l16]      = f2bf(v0);
                qk[n*DHEAD + 16 + l16] = f2bf(v1);
            } else {
                int kb = n >> 7, ki = n & 127;
                int kp2 = kb*128 + (ki & 15)*8 + (ki >> 4);
                vt[l16*NTOK + kp2]       = f2bf(v0);
                vt[(16+l16)*NTOK + kp2]  = f2bf(v1);
            }
        }
    }
}

// ---------------------------------------------------------------------------
// Kernel 2: cross attention, max-free softmax (linear partials).
// Block = 4 waves = (q-half 0/1) x (key-half 0/1): wave (qh,kh) does 32 q-rows
// over 2048 keys. K,V fragments direct from global (L1/L2; barrier per kt
// keeps waves tile-aligned); P per-wave LDS round-trip. End: key-halves merge
// O/l partials through LDS. grid (64,8,2) = 1024 blocks = 4/CU.
// ---------------------------------------------------------------------------
__global__ __launch_bounds__(256, 4) void attn_kernel(
    const unsigned short* __restrict__ ws, float* __restrict__ out)
{
    __shared__ unsigned short plds[4*32*136];   // per-wave 32 q x 128 k'

    const int X  = blockIdx.z;
    const int h  = blockIdx.y;
    const int qb = blockIdx.x;                  // 64 q-rows per block
    const int qinp = 1 - X, kvinp = X;
    const int tid  = threadIdx.x;
    const int lane = tid & 63;
    const int w    = tid >> 6;
    const int qh   = w & 1;                     // q-half
    const int kh   = w >> 1;                    // key-half
    const int quad = lane >> 4;
    const int l16  = lane & 15;

    const unsigned short* qbase = ws + QOFF + ((qinp*HEADS + h)*NTOK)*DHEAD;
    const unsigned short* kbase = ws + KOFF + ((kvinp*HEADS + h)*NTOK)*DHEAD;
    const unsigned short* vbase = ws + VOFF + ((kvinp*HEADS + h)*DHEAD)*NTOK;

    const int q0 = qb*64 + qh*32;
    const short8 qf0 = *reinterpret_cast<const short8*>(qbase + (q0 + l16)*DHEAD      + quad*8);
    const short8 qf1 = *reinterpret_cast<const short8*>(qbase + (q0 + 16 + l16)*DHEAD + quad*8);

    // fragment base pointers for this wave's 2048-key strip
    const unsigned short* kp  = kbase + (kh*2048 + l16)*DHEAD + quad*8;
    const unsigned short* vp0 = vbase + l16*NTOK      + kh*2048 + quad*8;
    const unsigned short* vp1 = vbase + (16+l16)*NTOK + kh*2048 + quad*8;

    float4v O00 = {0,0,0,0}, O01 = {0,0,0,0}, O10 = {0,0,0,0}, O11 = {0,0,0,0};
    float rs[2][4];
#pragma unroll
    for (int s = 0; s < 2; s++)
#pragma unroll
        for (int i = 0; i < 4; i++) rs[s][i] = 0.f;

    unsigned short* pw = plds + w*(32*136);

    for (int j = 0; j < 16; j++) {
        __syncthreads();    // keep the block's waves tile-aligned (L1 reuse)

        // S = Q K^T : K-fragments straight from global
        float4v S0[8], S1[8];
#pragma unroll
        for (int t = 0; t < 8; t++) {
            short8 kf = *reinterpret_cast<const short8*>(kp + (j*128 + t*16)*DHEAD);
            float4v z = {0,0,0,0};
            S0[t] = __builtin_amdgcn_mfma_f32_16x16x32_bf16(qf0, kf, z, 0,0,0);
            S1[t] = __builtin_amdgcn_mfma_f32_16x16x32_bf16(qf1, kf, z, 0,0,0);
        }

        // p = exp2(S); pack pairs -> one b128 write per row (per-wave region)
#pragma unroll
        for (int s = 0; s < 2; s++) {
#pragma unroll
            for (int i = 0; i < 4; i++) {
                uint4v wv;
#pragma unroll
                for (int t4 = 0; t4 < 4; t4++) {
                    float pa = __builtin_amdgcn_exp2f(s ? S1[2*t4][i]   : S0[2*t4][i]);
                    float pb = __builtin_amdgcn_exp2f(s ? S1[2*t4+1][i] : S0[2*t4+1][i]);
                    rs[s][i] += pa + pb;
                    union { float f; unsigned u; } ua, ub;
                    ua.f = pa; ub.f = pb;
                    wv[t4] = __builtin_amdgcn_perm(ub.u + 0x8000u, ua.u + 0x8000u,
                                                   0x07060302u);
                }
                *reinterpret_cast<uint4v*>(pw + (s*16 + quad*4 + i)*136 + l16*8) = wv;
            }
        }

        // O += P V : P A-frags from per-wave LDS, V B-frags from global
#pragma unroll
        for (int kk = 0; kk < 4; kk++) {
            short8 p0 = *reinterpret_cast<const short8*>(pw + l16*136      + kk*32 + quad*8);
            short8 p1 = *reinterpret_cast<const short8*>(pw + (16+l16)*136 + kk*32 + quad*8);
            short8 v0 = *reinterpret_cast<const short8*>(vp0 + j*128 + kk*32);
            short8 v1 = *reinterpret_cast<const short8*>(vp1 + j*128 + kk*32);
            O00 = __builtin_amdgcn_mfma_f32_16x16x32_bf16(p0, v0, O00, 0,0,0);
            O01 = __builtin_amdgcn_mfma_f32_16x16x32_bf16(p0, v1, O01, 0,0,0);
            O10 = __builtin_amdgcn_mfma_f32_16x16x32_bf16(p1, v0, O10, 0,0,0);
            O11 = __builtin_amdgcn_mfma_f32_16x16x32_bf16(p1, v1, O11, 0,0,0);
        }
    }

    // per-row partial l
    float lsum[2][4];
#pragma unroll
    for (int s = 0; s < 2; s++)
#pragma unroll
        for (int i = 0; i < 4; i++) {
            float l = rs[s][i];
#pragma unroll
            for (int m = 1; m < 16; m <<= 1) l += __shfl_xor(l, m);
            lsum[s][i] = l;
        }

    __syncthreads();    // all plds P reads complete before aliasing as combine buf

    // combine key-halves through LDS: layout [qh][32 rows][34 floats] (col 32 = l)
    float* comb = reinterpret_cast<float*>(plds) + qh*(32*34);
    if (kh == 1) {
#pragma unroll
        for (int s = 0; s < 2; s++)
#pragma unroll
            for (int i = 0; i < 4; i++) {
                int row = s*16 + quad*4 + i;
                comb[row*34 + l16]      = (s ? O10[i] : O00[i]);
                comb[row*34 + 16 + l16] = (s ? O11[i] : O01[i]);
                if (l16 == 0) comb[row*34 + 32] = lsum[s][i];
            }
    }
    __syncthreads();

    if (kh == 0) {
        float* ob = out + (size_t)X*NTOK*CDIM + h*DHEAD;
#pragma unroll
        for (int s = 0; s < 2; s++) {
#pragma unroll
            for (int i = 0; i < 4; i++) {
                int row = s*16 + quad*4 + i;
                float l = lsum[s][i] + comb[row*34 + 32];
                float inv = 1.0f / l;
                float a = ((s ? O10[i] : O00[i]) + comb[row*34 + l16])      * inv;
                float b = ((s ? O11[i] : O01[i]) + comb[row*34 + 16 + l16]) * inv;
                int orow = q0 + row;
                ob[orow*CDIM + l16]      = a;
                ob[orow*CDIM + 16 + l16] = b;
            }
        }
    }
}

extern "C" void kernel_launch(void* const* d_in, const int* in_sizes, int n_in,
                              void* d_out, int out_size, void* d_ws, size_t ws_size,
                              hipStream_t stream)
{
    const float* before = (const float*)d_in[0];
    const float* after  = (const float*)d_in[1];
    const float* W      = (const float*)d_in[2];
    const float* gamma  = (const float*)d_in[3];
    const float* beta   = (const float*)d_in[4];
    float* out          = (float*)d_out;
    unsigned short* ws  = (unsigned short*)d_ws;   // needs ~13.0 MB

    hipLaunchKernelGGL(wconv_kernel, dim3(96), dim3(256), 0, stream, W, ws);
    hipLaunchKernelGGL(qkv_ln_kernel, dim3(1024), dim3(256), 0, stream,
                       before, after, gamma, beta, ws);
    hipLaunchKernelGGL(attn_kernel, dim3(64, 8, 2), dim3(256), 0, stream, ws, out);
}

// Round 6
// 198.056 us; speedup vs baseline: 1.3996x; 1.1414x over previous
//
#include <hip/hip_runtime.h>

// Shapes: B=1, N=4096, C=256, H=8, d=32.
// ws layout (ushort elems):
//   Q[2][8][4096][32]          @ 0         (Q pre-scaled by d^-0.5*log2e)
//   K[2][8][4096][32]          @ KOFF
//   Vt[2][8][32][4096]         @ VOFF      (key dim permuted per 128-block:
//                                           k' = (k&15)*8 + (k>>4))
//   WBF[24][8192]              @ WOFF      (W bf16, swizzled to B-frag order)

typedef __attribute__((ext_vector_type(8))) short short8;
typedef __attribute__((ext_vector_type(4))) float float4v;
typedef __attribute__((ext_vector_type(2))) unsigned int uint2v;

#define NTOK 4096
#define CDIM 256
#define HEADS 8
#define DHEAD 32

#define QOFF 0
#define KOFF (2*HEADS*NTOK*DHEAD)
#define VOFF (2*(2*HEADS*NTOK*DHEAD))
#define WOFF (3*(2*HEADS*NTOK*DHEAD))

__device__ inline unsigned short f2bf(float f) {
    union { float f; unsigned u; } v; v.f = f;
    unsigned r = v.u + 0x7FFFu + ((v.u >> 16) & 1u);   // RNE
    return (unsigned short)(r >> 16);
}

// ---------------------------------------------------------------------------
// Kernel 0: W fp32 -> bf16, swizzled so a B-fragment is one contiguous 16B
// load: WBF[o32*8192 + (kk*2+nhalf)*512 + (quad*16+l16)*8 + j]
// ---------------------------------------------------------------------------
__global__ __launch_bounds__(256) void wconv_kernel(
    const float* __restrict__ W, unsigned short* __restrict__ ws)
{
    int idx = blockIdx.x*256 + threadIdx.x;    // [0, 24576): (row, col-octet)
    int R = idx >> 5, oct = idx & 31;
    int C = oct * 8;
    const float4* p = reinterpret_cast<const float4*>(W + R*CDIM + C);
    float4 a = p[0], b = p[1];
    short8 f;
    f[0]=(short)f2bf(a.x); f[1]=(short)f2bf(a.y); f[2]=(short)f2bf(a.z); f[3]=(short)f2bf(a.w);
    f[4]=(short)f2bf(b.x); f[5]=(short)f2bf(b.y); f[6]=(short)f2bf(b.z); f[7]=(short)f2bf(b.w);
    int o32 = R >> 5, r = R & 31;
    int kk = C >> 5, quad = (C >> 3) & 3;
    int dst = o32*8192 + (kk*2 + (r>>4))*512 + (quad*16 + (r&15))*8;
    *reinterpret_cast<short8*>(ws + WOFF + dst) = f;
}

// ---------------------------------------------------------------------------
// Kernel 1: t = x @ W^T (bf16 MFMA) + LayerNorm over d=32 groups.
// No LDS/barriers. grid = 1024: (row-tile 0..127) x (o-eighth 0..7, 3 o32s).
// ---------------------------------------------------------------------------
__global__ __launch_bounds__(256) void qkv_ln_kernel(
    const float* __restrict__ before, const float* __restrict__ after,
    const float* __restrict__ gamma, const float* __restrict__ beta,
    unsigned short* __restrict__ ws)
{
    const int tid  = threadIdx.x;
    const int lane = tid & 63;
    const int w    = tid >> 6;
    const int quad = lane >> 4;
    const int l16  = lane & 15;
    const int rt   = blockIdx.x >> 3;
    const int oq   = blockIdx.x & 7;

    const int mrow_frag = rt*64 + w*16 + l16;
    const int inp_f = mrow_frag >> 12;
    const int n_f   = mrow_frag & 4095;
    const float* x = inp_f ? after : before;

    short8 afrag[8];
#pragma unroll
    for (int kk = 0; kk < 8; kk++) {
        const float4* p = reinterpret_cast<const float4*>(x + n_f*CDIM + kk*32 + quad*8);
        float4 a = p[0], b = p[1];
        short8 f;
        f[0]=(short)f2bf(a.x); f[1]=(short)f2bf(a.y); f[2]=(short)f2bf(a.z); f[3]=(short)f2bf(a.w);
        f[4]=(short)f2bf(b.x); f[5]=(short)f2bf(b.y); f[6]=(short)f2bf(b.z); f[7]=(short)f2bf(b.w);
        afrag[kk] = f;
    }

    const float g0  = gamma[l16], g1  = gamma[16+l16];
    const float be0 = beta[l16],  be1 = beta[16+l16];
    const float cscale = 0.17677669529663687f * 1.4426950408889634f; // d^-0.5*log2e

    const int mrow_out  = rt*64 + w*16 + quad*4;
    const int inp_o     = mrow_out >> 12;
    const int n_o_base  = mrow_out & 4095;

    const unsigned short* wbf = ws + WOFF;

    for (int o32 = oq*3; o32 < oq*3 + 3; o32++) {
        const unsigned short* wb = wbf + o32*8192 + lane*8;
        float4v acc0 = {0.f,0.f,0.f,0.f}, acc1 = {0.f,0.f,0.f,0.f};
#pragma unroll
        for (int kk = 0; kk < 8; kk++) {
            short8 b0 = *reinterpret_cast<const short8*>(wb + (kk*2    )*512);
            short8 b1 = *reinterpret_cast<const short8*>(wb + (kk*2 + 1)*512);
            acc0 = __builtin_amdgcn_mfma_f32_16x16x32_bf16(afrag[kk], b0, acc0, 0,0,0);
            acc1 = __builtin_amdgcn_mfma_f32_16x16x32_bf16(afrag[kk], b1, acc1, 0,0,0);
        }

        const int which = o32 >> 3;     // 0=q 1=k 2=v
        const int h     = o32 & 7;
        unsigned short* qk = ws + (which == 0 ? QOFF : KOFF) + ((inp_o*HEADS + h)*NTOK)*DHEAD;
        unsigned short* vt = ws + VOFF + ((inp_o*HEADS + h)*DHEAD)*NTOK;
        const float qs = (which == 0) ? cscale : 1.0f;

#pragma unroll
        for (int i = 0; i < 4; i++) {
            float sum = acc0[i] + acc1[i];
            float sq  = acc0[i]*acc0[i] + acc1[i]*acc1[i];
#pragma unroll
            for (int m = 1; m < 16; m <<= 1) {
                sum += __shfl_xor(sum, m);
                sq  += __shfl_xor(sq,  m);
            }
            float mu   = sum * (1.0f/32.0f);
            float var  = sq * (1.0f/32.0f) - mu*mu;
            float rstd = rsqrtf(var + 1e-5f);
            float v0 = ((acc0[i]-mu)*rstd*g0 + be0) * qs;
            float v1 = ((acc1[i]-mu)*rstd*g1 + be1) * qs;
            int n = n_o_base + i;
            if (which < 2) {
                qk[n*DHEAD + l16]      = f2bf(v0);
                qk[n*DHEAD + 16 + l16] = f2bf(v1);
            } else {
                int kb = n >> 7, ki = n & 127;
                int kp2 = kb*128 + (ki & 15)*8 + (ki >> 4);
                vt[l16*NTOK + kp2]       = f2bf(v0);
                vt[(16+l16)*NTOK + kp2]  = f2bf(v1);
            }
        }
    }
}

// ---------------------------------------------------------------------------
// Kernel 2: cross attention, max-free softmax (linear partials).
// Block = 4 waves = (q-half) x (key-half): wave (qh,kh) does 32 q-rows over
// 2048 keys. K,V fragments direct from global; P per-wave LDS round-trip.
// S processed in 2 groups of 4 tiles to keep live regs < 128 (no spill at
// 4 waves/EU — R4's spill was the 122 MB WRITE_SIZE). End: key-halves merge
// O/l partials through LDS. grid (64,8,2) = 1024 blocks = 4/CU.
// ---------------------------------------------------------------------------
__global__ __launch_bounds__(256, 4) void attn_kernel(
    const unsigned short* __restrict__ ws, float* __restrict__ out)
{
    __shared__ unsigned short plds[4*32*136];   // per-wave 32 q x 128 k'

    const int X  = blockIdx.z;
    const int h  = blockIdx.y;
    const int qb = blockIdx.x;                  // 64 q-rows per block
    const int qinp = 1 - X, kvinp = X;
    const int tid  = threadIdx.x;
    const int lane = tid & 63;
    const int w    = tid >> 6;
    const int qh   = w & 1;                     // q-half
    const int kh   = w >> 1;                    // key-half
    const int quad = lane >> 4;
    const int l16  = lane & 15;

    const unsigned short* qbase = ws + QOFF + ((qinp*HEADS + h)*NTOK)*DHEAD;
    const unsigned short* kbase = ws + KOFF + ((kvinp*HEADS + h)*NTOK)*DHEAD;
    const unsigned short* vbase = ws + VOFF + ((kvinp*HEADS + h)*DHEAD)*NTOK;

    const int q0 = qb*64 + qh*32;
    const short8 qf0 = *reinterpret_cast<const short8*>(qbase + (q0 + l16)*DHEAD      + quad*8);
    const short8 qf1 = *reinterpret_cast<const short8*>(qbase + (q0 + 16 + l16)*DHEAD + quad*8);

    // fragment base pointers for this wave's 2048-key strip
    const unsigned short* kp  = kbase + (kh*2048 + l16)*DHEAD + quad*8;
    const unsigned short* vp0 = vbase + l16*NTOK      + kh*2048 + quad*8;
    const unsigned short* vp1 = vbase + (16+l16)*NTOK + kh*2048 + quad*8;

    float4v O00 = {0,0,0,0}, O01 = {0,0,0,0}, O10 = {0,0,0,0}, O11 = {0,0,0,0};
    float rs[2][4];
#pragma unroll
    for (int s = 0; s < 2; s++)
#pragma unroll
        for (int i = 0; i < 4; i++) rs[s][i] = 0.f;

    unsigned short* pw = plds + w*(32*136);

    for (int j = 0; j < 16; j++) {
        __syncthreads();    // keep the block's waves tile-aligned (L1 reuse)

        // S = Q K^T in two groups of 4 tiles (halves live S registers)
#pragma unroll
        for (int g = 0; g < 2; g++) {
            float4v S0[4], S1[4];
#pragma unroll
            for (int t = 0; t < 4; t++) {
                short8 kf = *reinterpret_cast<const short8*>(kp + (j*128 + g*64 + t*16)*DHEAD);
                float4v z = {0,0,0,0};
                S0[t] = __builtin_amdgcn_mfma_f32_16x16x32_bf16(qf0, kf, z, 0,0,0);
                S1[t] = __builtin_amdgcn_mfma_f32_16x16x32_bf16(qf1, kf, z, 0,0,0);
            }
            // p = exp2(S); pack pairs -> one b64 write per row per group.
            // Lane's values for tile t sit at k' = l16*8 + g*4 + t.
#pragma unroll
            for (int s = 0; s < 2; s++) {
#pragma unroll
                for (int i = 0; i < 4; i++) {
                    uint2v wv;
#pragma unroll
                    for (int t4 = 0; t4 < 2; t4++) {
                        float pa = __builtin_amdgcn_exp2f(s ? S1[2*t4][i]   : S0[2*t4][i]);
                        float pb = __builtin_amdgcn_exp2f(s ? S1[2*t4+1][i] : S0[2*t4+1][i]);
                        rs[s][i] += pa + pb;
                        union { float f; unsigned u; } ua, ub;
                        ua.f = pa; ub.f = pb;
                        wv[t4] = __builtin_amdgcn_perm(ub.u + 0x8000u, ua.u + 0x8000u,
                                                       0x07060302u);
                    }
                    *reinterpret_cast<uint2v*>(pw + (s*16 + quad*4 + i)*136 + l16*8 + g*4) = wv;
                }
            }
        }

        // O += P V : P A-frags from per-wave LDS, V B-frags from global
#pragma unroll
        for (int kk = 0; kk < 4; kk++) {
            short8 p0 = *reinterpret_cast<const short8*>(pw + l16*136      + kk*32 + quad*8);
            short8 p1 = *reinterpret_cast<const short8*>(pw + (16+l16)*136 + kk*32 + quad*8);
            short8 v0 = *reinterpret_cast<const short8*>(vp0 + j*128 + kk*32);
            short8 v1 = *reinterpret_cast<const short8*>(vp1 + j*128 + kk*32);
            O00 = __builtin_amdgcn_mfma_f32_16x16x32_bf16(p0, v0, O00, 0,0,0);
            O01 = __builtin_amdgcn_mfma_f32_16x16x32_bf16(p0, v1, O01, 0,0,0);
            O10 = __builtin_amdgcn_mfma_f32_16x16x32_bf16(p1, v0, O10, 0,0,0);
            O11 = __builtin_amdgcn_mfma_f32_16x16x32_bf16(p1, v1, O11, 0,0,0);
        }
    }

    // per-row partial l
    float lsum[2][4];
#pragma unroll
    for (int s = 0; s < 2; s++)
#pragma unroll
        for (int i = 0; i < 4; i++) {
            float l = rs[s][i];
#pragma unroll
            for (int m = 1; m < 16; m <<= 1) l += __shfl_xor(l, m);
            lsum[s][i] = l;
        }

    __syncthreads();    // all plds P reads complete before aliasing as combine buf

    // combine key-halves through LDS: layout [qh][32 rows][34 floats] (col 32 = l)
    float* comb = reinterpret_cast<float*>(plds) + qh*(32*34);
    if (kh == 1) {
#pragma unroll
        for (int s = 0; s < 2; s++)
#pragma unroll
            for (int i = 0; i < 4; i++) {
                int row = s*16 + quad*4 + i;
                comb[row*34 + l16]      = (s ? O10[i] : O00[i]);
                comb[row*34 + 16 + l16] = (s ? O11[i] : O01[i]);
                if (l16 == 0) comb[row*34 + 32] = lsum[s][i];
            }
    }
    __syncthreads();

    if (kh == 0) {
        float* ob = out + (size_t)X*NTOK*CDIM + h*DHEAD;
#pragma unroll
        for (int s = 0; s < 2; s++) {
#pragma unroll
            for (int i = 0; i < 4; i++) {
                int row = s*16 + quad*4 + i;
                float l = lsum[s][i] + comb[row*34 + 32];
                float inv = 1.0f / l;
                float a = ((s ? O10[i] : O00[i]) + comb[row*34 + l16])      * inv;
                float b = ((s ? O11[i] : O01[i]) + comb[row*34 + 16 + l16]) * inv;
                int orow = q0 + row;
                ob[orow*CDIM + l16]      = a;
                ob[orow*CDIM + 16 + l16] = b;
            }
        }
    }
}

extern "C" void kernel_launch(void* const* d_in, const int* in_sizes, int n_in,
                              void* d_out, int out_size, void* d_ws, size_t ws_size,
                              hipStream_t stream)
{
    const float* before = (const float*)d_in[0];
    const float* after  = (const float*)d_in[1];
    const float* W      = (const float*)d_in[2];
    const float* gamma  = (const float*)d_in[3];
    const float* beta   = (const float*)d_in[4];
    float* out          = (float*)d_out;
    unsigned short* ws  = (unsigned short*)d_ws;   // needs ~13.0 MB

    hipLaunchKernelGGL(wconv_kernel, dim3(96), dim3(256), 0, stream, W, ws);
    hipLaunchKernelGGL(qkv_ln_kernel, dim3(1024), dim3(256), 0, stream,
                       before, after, gamma, beta, ws);
    hipLaunchKernelGGL(attn_kernel, dim3(64, 8, 2), dim3(256), 0, stream, ws, out);
}

// Round 7
// 162.168 us; speedup vs baseline: 1.7094x; 1.2213x over previous
//
#include <hip/hip_runtime.h>

// Shapes: B=1, N=4096, C=256, H=8, d=32.
// ws layout (ushort elems):
//   Q[2][8][4096][32]          @ 0         (Q pre-scaled by d^-0.5*log2e)
//   K[2][8][4096][32]          @ KOFF
//   Vt[2][8][32][4096]         @ VOFF      (key dim permuted per 64-block:
//                                           k' = (ki&15)*4 + (ki>>4))
//   WBF[24][8192]              @ WOFF      (W bf16, swizzled to B-frag order)

typedef __attribute__((ext_vector_type(8))) short short8;
typedef __attribute__((ext_vector_type(4))) float float4v;
typedef __attribute__((ext_vector_type(2))) unsigned int uint2v;

#define NTOK 4096
#define CDIM 256
#define HEADS 8
#define DHEAD 32

#define QOFF 0
#define KOFF (2*HEADS*NTOK*DHEAD)
#define VOFF (2*(2*HEADS*NTOK*DHEAD))
#define WOFF (3*(2*HEADS*NTOK*DHEAD))

__device__ inline unsigned short f2bf(float f) {
    union { float f; unsigned u; } v; v.f = f;
    unsigned r = v.u + 0x7FFFu + ((v.u >> 16) & 1u);   // RNE
    return (unsigned short)(r >> 16);
}

// ---------------------------------------------------------------------------
// Kernel 0: W fp32 -> bf16, swizzled so a B-fragment is one contiguous 16B
// load: WBF[o32*8192 + (kk*2+nhalf)*512 + (quad*16+l16)*8 + j]
// ---------------------------------------------------------------------------
__global__ __launch_bounds__(256) void wconv_kernel(
    const float* __restrict__ W, unsigned short* __restrict__ ws)
{
    int idx = blockIdx.x*256 + threadIdx.x;    // [0, 24576): (row, col-octet)
    int R = idx >> 5, oct = idx & 31;
    int C = oct * 8;
    const float4* p = reinterpret_cast<const float4*>(W + R*CDIM + C);
    float4 a = p[0], b = p[1];
    short8 f;
    f[0]=(short)f2bf(a.x); f[1]=(short)f2bf(a.y); f[2]=(short)f2bf(a.z); f[3]=(short)f2bf(a.w);
    f[4]=(short)f2bf(b.x); f[5]=(short)f2bf(b.y); f[6]=(short)f2bf(b.z); f[7]=(short)f2bf(b.w);
    int o32 = R >> 5, r = R & 31;
    int kk = C >> 5, quad = (C >> 3) & 3;
    int dst = o32*8192 + (kk*2 + (r>>4))*512 + (quad*16 + (r&15))*8;
    *reinterpret_cast<short8*>(ws + WOFF + dst) = f;
}

// ---------------------------------------------------------------------------
// Kernel 1: t = x @ W^T (bf16 MFMA) + LayerNorm over d=32 groups.
// No LDS/barriers. grid = 1024: (row-tile 0..127) x (o-eighth 0..7, 3 o32s).
// ---------------------------------------------------------------------------
__global__ __launch_bounds__(256) void qkv_ln_kernel(
    const float* __restrict__ before, const float* __restrict__ after,
    const float* __restrict__ gamma, const float* __restrict__ beta,
    unsigned short* __restrict__ ws)
{
    const int tid  = threadIdx.x;
    const int lane = tid & 63;
    const int w    = tid >> 6;
    const int quad = lane >> 4;
    const int l16  = lane & 15;
    const int rt   = blockIdx.x >> 3;
    const int oq   = blockIdx.x & 7;

    const int mrow_frag = rt*64 + w*16 + l16;
    const int inp_f = mrow_frag >> 12;
    const int n_f   = mrow_frag & 4095;
    const float* x = inp_f ? after : before;

    short8 afrag[8];
#pragma unroll
    for (int kk = 0; kk < 8; kk++) {
        const float4* p = reinterpret_cast<const float4*>(x + n_f*CDIM + kk*32 + quad*8);
        float4 a = p[0], b = p[1];
        short8 f;
        f[0]=(short)f2bf(a.x); f[1]=(short)f2bf(a.y); f[2]=(short)f2bf(a.z); f[3]=(short)f2bf(a.w);
        f[4]=(short)f2bf(b.x); f[5]=(short)f2bf(b.y); f[6]=(short)f2bf(b.z); f[7]=(short)f2bf(b.w);
        afrag[kk] = f;
    }

    const float g0  = gamma[l16], g1  = gamma[16+l16];
    const float be0 = beta[l16],  be1 = beta[16+l16];
    const float cscale = 0.17677669529663687f * 1.4426950408889634f; // d^-0.5*log2e

    const int mrow_out  = rt*64 + w*16 + quad*4;
    const int inp_o     = mrow_out >> 12;
    const int n_o_base  = mrow_out & 4095;

    const unsigned short* wbf = ws + WOFF;

    for (int o32 = oq*3; o32 < oq*3 + 3; o32++) {
        const unsigned short* wb = wbf + o32*8192 + lane*8;
        float4v acc0 = {0.f,0.f,0.f,0.f}, acc1 = {0.f,0.f,0.f,0.f};
#pragma unroll
        for (int kk = 0; kk < 8; kk++) {
            short8 b0 = *reinterpret_cast<const short8*>(wb + (kk*2    )*512);
            short8 b1 = *reinterpret_cast<const short8*>(wb + (kk*2 + 1)*512);
            acc0 = __builtin_amdgcn_mfma_f32_16x16x32_bf16(afrag[kk], b0, acc0, 0,0,0);
            acc1 = __builtin_amdgcn_mfma_f32_16x16x32_bf16(afrag[kk], b1, acc1, 0,0,0);
        }

        const int which = o32 >> 3;     // 0=q 1=k 2=v
        const int h     = o32 & 7;
        unsigned short* qk = ws + (which == 0 ? QOFF : KOFF) + ((inp_o*HEADS + h)*NTOK)*DHEAD;
        unsigned short* vt = ws + VOFF + ((inp_o*HEADS + h)*DHEAD)*NTOK;
        const float qs = (which == 0) ? cscale : 1.0f;

#pragma unroll
        for (int i = 0; i < 4; i++) {
            float sum = acc0[i] + acc1[i];
            float sq  = acc0[i]*acc0[i] + acc1[i]*acc1[i];
#pragma unroll
            for (int m = 1; m < 16; m <<= 1) {
                sum += __shfl_xor(sum, m);
                sq  += __shfl_xor(sq,  m);
            }
            float mu   = sum * (1.0f/32.0f);
            float var  = sq * (1.0f/32.0f) - mu*mu;
            float rstd = rsqrtf(var + 1e-5f);
            float v0 = ((acc0[i]-mu)*rstd*g0 + be0) * qs;
            float v1 = ((acc1[i]-mu)*rstd*g1 + be1) * qs;
            int n = n_o_base + i;
            if (which < 2) {
                qk[n*DHEAD + l16]      = f2bf(v0);
                qk[n*DHEAD + 16 + l16] = f2bf(v1);
            } else {
                int kb = n >> 6, ki = n & 63;        // within-64 permutation
                int kp2 = kb*64 + (ki & 15)*4 + (ki >> 4);
                vt[l16*NTOK + kp2]       = f2bf(v0);
                vt[(16+l16)*NTOK + kp2]  = f2bf(v1);
            }
        }
    }
}

// ---------------------------------------------------------------------------
// Kernel 2: cross attention, max-free softmax (linear partials).
// Block = 4 waves = (q-half) x (key-half): wave (qh,kh) does 32 q-rows over
// 2048 keys. K frags direct from global; V staged in LDS per key-half
// (single-buffered); P round-trips per-wave LDS in 64-key chunks (halves
// live S regs and plds). End: key-halves merge O/l partials through LDS.
// grid (64,8,2) = 1024 blocks; LDS 35.8 KB -> 4 blocks/CU = 16 waves/CU.
// ---------------------------------------------------------------------------
__global__ __launch_bounds__(256, 4) void attn_kernel(
    const unsigned short* __restrict__ ws, float* __restrict__ out)
{
    __shared__ unsigned short vlds[2][32*136];   // per key-half: 32 d x 128 k'
    __shared__ unsigned short plds[4][32*72];    // per wave: 32 q x 64 k' chunk

    const int X  = blockIdx.z;
    const int h  = blockIdx.y;
    const int qb = blockIdx.x;                  // 64 q-rows per block
    const int qinp = 1 - X, kvinp = X;
    const int tid  = threadIdx.x;
    const int lane = tid & 63;
    const int w    = tid >> 6;
    const int qh   = w & 1;                     // q-half
    const int kh   = w >> 1;                    // key-half
    const int quad = lane >> 4;
    const int l16  = lane & 15;

    const unsigned short* qbase = ws + QOFF + ((qinp*HEADS + h)*NTOK)*DHEAD;
    const unsigned short* kbase = ws + KOFF + ((kvinp*HEADS + h)*NTOK)*DHEAD;
    const unsigned short* vbase = ws + VOFF + ((kvinp*HEADS + h)*DHEAD)*NTOK;

    const int q0 = qb*64 + qh*32;
    const short8 qf0 = *reinterpret_cast<const short8*>(qbase + (q0 + l16)*DHEAD      + quad*8);
    const short8 qf1 = *reinterpret_cast<const short8*>(qbase + (q0 + 16 + l16)*DHEAD + quad*8);

    const unsigned short* kp   = kbase + (kh*2048 + l16)*DHEAD + quad*8;
    const unsigned short* vsrc = vbase + kh*2048;   // rows stride NTOK

    float4v O00 = {0,0,0,0}, O01 = {0,0,0,0}, O10 = {0,0,0,0}, O11 = {0,0,0,0};
    float rs[2][4];
#pragma unroll
    for (int s = 0; s < 2; s++)
#pragma unroll
        for (int i = 0; i < 4; i++) rs[s][i] = 0.f;

    unsigned short* pw  = plds[w];
    unsigned short* vh  = vlds[kh];
    const int t2 = qh*64 + lane;                // 0..127 within the kh pair

    for (int j = 0; j < 16; j++) {
        __syncthreads();    // prior PV reads of vlds complete
        // stage vlds[kh]: 32 d-rows x 128 k' cols; 128 threads x 4 stores
#pragma unroll
        for (int r = 0; r < 4; r++) {
            int c = t2 + 128*r;                 // 0..511
            short8 d = *reinterpret_cast<const short8*>(vsrc + (c>>4)*NTOK + j*128 + (c&15)*8);
            *reinterpret_cast<short8*>(vh + (c>>4)*136 + (c&15)*8) = d;
        }
        __syncthreads();

#pragma unroll
        for (int c = 0; c < 2; c++) {           // 64-key chunks
            float4v S0[4], S1[4];
#pragma unroll
            for (int t = 0; t < 4; t++) {
                short8 kf = *reinterpret_cast<const short8*>(kp + (j*128 + c*64 + t*16)*DHEAD);
                float4v z = {0,0,0,0};
                S0[t] = __builtin_amdgcn_mfma_f32_16x16x32_bf16(qf0, kf, z, 0,0,0);
                S1[t] = __builtin_amdgcn_mfma_f32_16x16x32_bf16(qf1, kf, z, 0,0,0);
            }
            // p = exp2(S); lane's 4 values per row at k' = l16*4 + t -> b64
#pragma unroll
            for (int s = 0; s < 2; s++) {
#pragma unroll
                for (int i = 0; i < 4; i++) {
                    uint2v wv;
#pragma unroll
                    for (int t4 = 0; t4 < 2; t4++) {
                        float pa = __builtin_amdgcn_exp2f(s ? S1[2*t4][i]   : S0[2*t4][i]);
                        float pb = __builtin_amdgcn_exp2f(s ? S1[2*t4+1][i] : S0[2*t4+1][i]);
                        rs[s][i] += pa + pb;
                        union { float f; unsigned u; } ua, ub;
                        ua.f = pa; ub.f = pb;
                        wv[t4] = __builtin_amdgcn_perm(ub.u + 0x8000u, ua.u + 0x8000u,
                                                       0x07060302u);
                    }
                    *reinterpret_cast<uint2v*>(pw + (s*16 + quad*4 + i)*72 + l16*4) = wv;
                }
            }
            // O += P V over this 64-key chunk (2 k-steps of 32)
#pragma unroll
            for (int kk = 0; kk < 2; kk++) {
                short8 p0 = *reinterpret_cast<const short8*>(pw + l16*72      + kk*32 + quad*8);
                short8 p1 = *reinterpret_cast<const short8*>(pw + (16+l16)*72 + kk*32 + quad*8);
                short8 v0 = *reinterpret_cast<const short8*>(vh + l16*136      + c*64 + kk*32 + quad*8);
                short8 v1 = *reinterpret_cast<const short8*>(vh + (16+l16)*136 + c*64 + kk*32 + quad*8);
                O00 = __builtin_amdgcn_mfma_f32_16x16x32_bf16(p0, v0, O00, 0,0,0);
                O01 = __builtin_amdgcn_mfma_f32_16x16x32_bf16(p0, v1, O01, 0,0,0);
                O10 = __builtin_amdgcn_mfma_f32_16x16x32_bf16(p1, v0, O10, 0,0,0);
                O11 = __builtin_amdgcn_mfma_f32_16x16x32_bf16(p1, v1, O11, 0,0,0);
            }
        }
    }

    // per-row partial l
    float lsum[2][4];
#pragma unroll
    for (int s = 0; s < 2; s++)
#pragma unroll
        for (int i = 0; i < 4; i++) {
            float l = rs[s][i];
#pragma unroll
            for (int m = 1; m < 16; m <<= 1) l += __shfl_xor(l, m);
            lsum[s][i] = l;
        }

    __syncthreads();    // all plds/vlds reads done before aliasing as combine buf

    // combine key-halves through LDS: [qh][32 rows][34 floats] (col 32 = l)
    float* comb = reinterpret_cast<float*>(&plds[0][0]) + qh*(32*34);
    if (kh == 1) {
#pragma unroll
        for (int s = 0; s < 2; s++)
#pragma unroll
            for (int i = 0; i < 4; i++) {
                int row = s*16 + quad*4 + i;
                comb[row*34 + l16]      = (s ? O10[i] : O00[i]);
                comb[row*34 + 16 + l16] = (s ? O11[i] : O01[i]);
                if (l16 == 0) comb[row*34 + 32] = lsum[s][i];
            }
    }
    __syncthreads();

    if (kh == 0) {
        float* ob = out + (size_t)X*NTOK*CDIM + h*DHEAD;
#pragma unroll
        for (int s = 0; s < 2; s++) {
#pragma unroll
            for (int i = 0; i < 4; i++) {
                int row = s*16 + quad*4 + i;
                float l = lsum[s][i] + comb[row*34 + 32];
                float inv = 1.0f / l;
                float a = ((s ? O10[i] : O00[i]) + comb[row*34 + l16])      * inv;
                float b = ((s ? O11[i] : O01[i]) + comb[row*34 + 16 + l16]) * inv;
                int orow = q0 + row;
                ob[orow*CDIM + l16]      = a;
                ob[orow*CDIM + 16 + l16] = b;
            }
        }
    }
}

extern "C" void kernel_launch(void* const* d_in, const int* in_sizes, int n_in,
                              void* d_out, int out_size, void* d_ws, size_t ws_size,
                              hipStream_t stream)
{
    const float* before = (const float*)d_in[0];
    const float* after  = (const float*)d_in[1];
    const float* W      = (const float*)d_in[2];
    const float* gamma  = (const float*)d_in[3];
    const float* beta   = (const float*)d_in[4];
    float* out          = (float*)d_out;
    unsigned short* ws  = (unsigned short*)d_ws;   // needs ~13.0 MB

    hipLaunchKernelGGL(wconv_kernel, dim3(96), dim3(256), 0, stream, W, ws);
    hipLaunchKernelGGL(qkv_ln_kernel, dim3(1024), dim3(256), 0, stream,
                       before, after, gamma, beta, ws);
    hipLaunchKernelGGL(attn_kernel, dim3(64, 8, 2), dim3(256), 0, stream, ws, out);
}

// Round 8
// 154.089 us; speedup vs baseline: 1.7990x; 1.0524x over previous
//
#include <hip/hip_runtime.h>

// Shapes: B=1, N=4096, C=256, H=8, d=32.
// ws layout (ushort elems):
//   Q[2][8][4096][32]          @ 0         (Q pre-scaled by d^-0.5*log2e)
//   K[2][8][4096][32]          @ KOFF
//   Vt[2][8][32][4096]         @ VOFF      (key dim permuted per 32-block to
//                                           PV A-frag slot order: ki<16 ->
//                                           (ki>>2)*8+(ki&3), else +4)
//   WBF[24][8192]              @ WOFF      (W bf16, swizzled to B-frag order)

typedef __attribute__((ext_vector_type(8))) short short8;
typedef __attribute__((ext_vector_type(4))) float float4v;
typedef __attribute__((ext_vector_type(4))) unsigned int uint4v;

#define NTOK 4096
#define CDIM 256
#define HEADS 8
#define DHEAD 32

#define QOFF 0
#define KOFF (2*HEADS*NTOK*DHEAD)
#define VOFF (2*(2*HEADS*NTOK*DHEAD))
#define WOFF (3*(2*HEADS*NTOK*DHEAD))

__device__ inline unsigned short f2bf(float f) {
    union { float f; unsigned u; } v; v.f = f;
    unsigned r = v.u + 0x7FFFu + ((v.u >> 16) & 1u);   // RNE
    return (unsigned short)(r >> 16);
}

// ---------------------------------------------------------------------------
// Kernel 0: W fp32 -> bf16, swizzled so a B-fragment is one contiguous 16B
// load: WBF[o32*8192 + (kk*2+nhalf)*512 + (quad*16+l16)*8 + j]
// ---------------------------------------------------------------------------
__global__ __launch_bounds__(256) void wconv_kernel(
    const float* __restrict__ W, unsigned short* __restrict__ ws)
{
    int idx = blockIdx.x*256 + threadIdx.x;    // [0, 24576): (row, col-octet)
    int R = idx >> 5, oct = idx & 31;
    int C = oct * 8;
    const float4* p = reinterpret_cast<const float4*>(W + R*CDIM + C);
    float4 a = p[0], b = p[1];
    short8 f;
    f[0]=(short)f2bf(a.x); f[1]=(short)f2bf(a.y); f[2]=(short)f2bf(a.z); f[3]=(short)f2bf(a.w);
    f[4]=(short)f2bf(b.x); f[5]=(short)f2bf(b.y); f[6]=(short)f2bf(b.z); f[7]=(short)f2bf(b.w);
    int o32 = R >> 5, r = R & 31;
    int kk = C >> 5, quad = (C >> 3) & 3;
    int dst = o32*8192 + (kk*2 + (r>>4))*512 + (quad*16 + (r&15))*8;
    *reinterpret_cast<short8*>(ws + WOFF + dst) = f;
}

// ---------------------------------------------------------------------------
// Kernel 1: t = x @ W^T (bf16 MFMA) + LayerNorm over d=32 groups.
// No LDS/barriers. grid = 1024: (row-tile 0..127) x (o-eighth 0..7, 3 o32s).
// ---------------------------------------------------------------------------
__global__ __launch_bounds__(256) void qkv_ln_kernel(
    const float* __restrict__ before, const float* __restrict__ after,
    const float* __restrict__ gamma, const float* __restrict__ beta,
    unsigned short* __restrict__ ws)
{
    const int tid  = threadIdx.x;
    const int lane = tid & 63;
    const int w    = tid >> 6;
    const int quad = lane >> 4;
    const int l16  = lane & 15;
    const int rt   = blockIdx.x >> 3;
    const int oq   = blockIdx.x & 7;

    const int mrow_frag = rt*64 + w*16 + l16;
    const int inp_f = mrow_frag >> 12;
    const int n_f   = mrow_frag & 4095;
    const float* x = inp_f ? after : before;

    short8 afrag[8];
#pragma unroll
    for (int kk = 0; kk < 8; kk++) {
        const float4* p = reinterpret_cast<const float4*>(x + n_f*CDIM + kk*32 + quad*8);
        float4 a = p[0], b = p[1];
        short8 f;
        f[0]=(short)f2bf(a.x); f[1]=(short)f2bf(a.y); f[2]=(short)f2bf(a.z); f[3]=(short)f2bf(a.w);
        f[4]=(short)f2bf(b.x); f[5]=(short)f2bf(b.y); f[6]=(short)f2bf(b.z); f[7]=(short)f2bf(b.w);
        afrag[kk] = f;
    }

    const float g0  = gamma[l16], g1  = gamma[16+l16];
    const float be0 = beta[l16],  be1 = beta[16+l16];
    const float cscale = 0.17677669529663687f * 1.4426950408889634f; // d^-0.5*log2e

    const int mrow_out  = rt*64 + w*16 + quad*4;
    const int inp_o     = mrow_out >> 12;
    const int n_o_base  = mrow_out & 4095;

    const unsigned short* wbf = ws + WOFF;

    for (int o32 = oq*3; o32 < oq*3 + 3; o32++) {
        const unsigned short* wb = wbf + o32*8192 + lane*8;
        float4v acc0 = {0.f,0.f,0.f,0.f}, acc1 = {0.f,0.f,0.f,0.f};
#pragma unroll
        for (int kk = 0; kk < 8; kk++) {
            short8 b0 = *reinterpret_cast<const short8*>(wb + (kk*2    )*512);
            short8 b1 = *reinterpret_cast<const short8*>(wb + (kk*2 + 1)*512);
            acc0 = __builtin_amdgcn_mfma_f32_16x16x32_bf16(afrag[kk], b0, acc0, 0,0,0);
            acc1 = __builtin_amdgcn_mfma_f32_16x16x32_bf16(afrag[kk], b1, acc1, 0,0,0);
        }

        const int which = o32 >> 3;     // 0=q 1=k 2=v
        const int h     = o32 & 7;
        unsigned short* qk = ws + (which == 0 ? QOFF : KOFF) + ((inp_o*HEADS + h)*NTOK)*DHEAD;
        unsigned short* vt = ws + VOFF + ((inp_o*HEADS + h)*DHEAD)*NTOK;
        const float qs = (which == 0) ? cscale : 1.0f;

#pragma unroll
        for (int i = 0; i < 4; i++) {
            float sum = acc0[i] + acc1[i];
            float sq  = acc0[i]*acc0[i] + acc1[i]*acc1[i];
#pragma unroll
            for (int m = 1; m < 16; m <<= 1) {
                sum += __shfl_xor(sum, m);
                sq  += __shfl_xor(sq,  m);
            }
            float mu   = sum * (1.0f/32.0f);
            float var  = sq * (1.0f/32.0f) - mu*mu;
            float rstd = rsqrtf(var + 1e-5f);
            float v0 = ((acc0[i]-mu)*rstd*g0 + be0) * qs;
            float v1 = ((acc1[i]-mu)*rstd*g1 + be1) * qs;
            int n = n_o_base + i;
            if (which < 2) {
                qk[n*DHEAD + l16]      = f2bf(v0);
                qk[n*DHEAD + 16 + l16] = f2bf(v1);
            } else {
                // PV A-frag slot order within each 32-key block:
                // ki<16: slot=(ki>>2)*8+(ki&3); ki>=16: slot=((ki-16)>>2)*8+4+(ki&3)
                int kb = n >> 5, ki = n & 31;
                int slot = ((ki & 15) >> 2)*8 + (ki & 3) + ((ki >> 4) << 2);
                int kp2 = kb*32 + slot;
                vt[l16*NTOK + kp2]       = f2bf(v0);
                vt[(16+l16)*NTOK + kp2]  = f2bf(v1);
            }
        }
    }
}

// ---------------------------------------------------------------------------
// Kernel 2: cross attention, max-free softmax, NO P LDS round-trip:
// S^T = K·Q^T lands in C-layout with col=q, row=key — each lane holds, for
// its q=l16, exactly the 8 keys of a PV A-fragment (given the V slot
// permutation above). exp+pack in registers feeds PV MFMA directly.
// Block = 4 waves = (q-half) x (key-half); V staged in LDS per key-half;
// key-halves merge O/l partials through LDS. grid (64,8,2) = 1024 blocks.
// ---------------------------------------------------------------------------
__global__ __launch_bounds__(256, 4) void attn_kernel(
    const unsigned short* __restrict__ ws, float* __restrict__ out)
{
    __shared__ unsigned short vlds[2][32*136];   // per key-half: 32 d x 128 k'

    const int X  = blockIdx.z;
    const int h  = blockIdx.y;
    const int qb = blockIdx.x;                  // 64 q-rows per block
    const int qinp = 1 - X, kvinp = X;
    const int tid  = threadIdx.x;
    const int lane = tid & 63;
    const int w    = tid >> 6;
    const int qh   = w & 1;                     // q-half
    const int kh   = w >> 1;                    // key-half
    const int quad = lane >> 4;
    const int l16  = lane & 15;

    const unsigned short* qbase = ws + QOFF + ((qinp*HEADS + h)*NTOK)*DHEAD;
    const unsigned short* kbase = ws + KOFF + ((kvinp*HEADS + h)*NTOK)*DHEAD;
    const unsigned short* vbase = ws + VOFF + ((kvinp*HEADS + h)*DHEAD)*NTOK;

    const int q0 = qb*64 + qh*32;
    // Q as B-operand: B[n=q=l16][k=d=quad*8+j]
    const short8 qf0 = *reinterpret_cast<const short8*>(qbase + (q0 + l16)*DHEAD      + quad*8);
    const short8 qf1 = *reinterpret_cast<const short8*>(qbase + (q0 + 16 + l16)*DHEAD + quad*8);

    // K as A-operand: A[m=key=l16 (within tile)][k=d=quad*8+j]
    const unsigned short* kp   = kbase + (kh*2048 + l16)*DHEAD + quad*8;
    const unsigned short* vsrc = vbase + kh*2048;   // rows stride NTOK

    float4v O00 = {0,0,0,0}, O01 = {0,0,0,0}, O10 = {0,0,0,0}, O11 = {0,0,0,0};
    float rs0 = 0.f, rs1 = 0.f;

    unsigned short* vh = vlds[kh];
    const int t2 = qh*64 + lane;                // 0..127 within the kh pair

    for (int j = 0; j < 16; j++) {
        __syncthreads();    // prior PV reads of vlds complete
        // stage vlds[kh]: 32 d-rows x 128 k' cols; 128 threads x 4 stores
#pragma unroll
        for (int r = 0; r < 4; r++) {
            int c = t2 + 128*r;                 // 0..511
            short8 d = *reinterpret_cast<const short8*>(vsrc + (c>>4)*NTOK + j*128 + (c&15)*8);
            *reinterpret_cast<short8*>(vh + (c>>4)*136 + (c&15)*8) = d;
        }
        __syncthreads();

#pragma unroll
        for (int grp = 0; grp < 4; grp++) {     // 32-key groups
            short8 kf0 = *reinterpret_cast<const short8*>(kp + (j*128 + grp*32     )*DHEAD);
            short8 kf1 = *reinterpret_cast<const short8*>(kp + (j*128 + grp*32 + 16)*DHEAD);
            short8 v0  = *reinterpret_cast<const short8*>(vh + l16*136      + grp*32 + quad*8);
            short8 v1  = *reinterpret_cast<const short8*>(vh + (16+l16)*136 + grp*32 + quad*8);
#pragma unroll
            for (int s = 0; s < 2; s++) {
                const short8 qf = s ? qf1 : qf0;
                float4v z = {0,0,0,0};
                float4v S0 = __builtin_amdgcn_mfma_f32_16x16x32_bf16(kf0, qf, z, 0,0,0);
                float4v S1 = __builtin_amdgcn_mfma_f32_16x16x32_bf16(kf1, qf, z, 0,0,0);
                // exp + pack straight into the PV A-fragment
                float e0 = __builtin_amdgcn_exp2f(S0[0]);
                float e1 = __builtin_amdgcn_exp2f(S0[1]);
                float e2 = __builtin_amdgcn_exp2f(S0[2]);
                float e3 = __builtin_amdgcn_exp2f(S0[3]);
                float e4 = __builtin_amdgcn_exp2f(S1[0]);
                float e5 = __builtin_amdgcn_exp2f(S1[1]);
                float e6 = __builtin_amdgcn_exp2f(S1[2]);
                float e7 = __builtin_amdgcn_exp2f(S1[3]);
                float rsum = ((e0+e1)+(e2+e3)) + ((e4+e5)+(e6+e7));
                if (s) rs1 += rsum; else rs0 += rsum;
                union { float f; unsigned u; } u0,u1,u2,u3,u4,u5,u6,u7;
                u0.f=e0; u1.f=e1; u2.f=e2; u3.f=e3; u4.f=e4; u5.f=e5; u6.f=e6; u7.f=e7;
                union { short8 s8; uint4v u4v; } pf;
                pf.u4v[0] = __builtin_amdgcn_perm(u1.u + 0x8000u, u0.u + 0x8000u, 0x07060302u);
                pf.u4v[1] = __builtin_amdgcn_perm(u3.u + 0x8000u, u2.u + 0x8000u, 0x07060302u);
                pf.u4v[2] = __builtin_amdgcn_perm(u5.u + 0x8000u, u4.u + 0x8000u, 0x07060302u);
                pf.u4v[3] = __builtin_amdgcn_perm(u7.u + 0x8000u, u6.u + 0x8000u, 0x07060302u);
                if (s == 0) {
                    O00 = __builtin_amdgcn_mfma_f32_16x16x32_bf16(pf.s8, v0, O00, 0,0,0);
                    O01 = __builtin_amdgcn_mfma_f32_16x16x32_bf16(pf.s8, v1, O01, 0,0,0);
                } else {
                    O10 = __builtin_amdgcn_mfma_f32_16x16x32_bf16(pf.s8, v0, O10, 0,0,0);
                    O11 = __builtin_amdgcn_mfma_f32_16x16x32_bf16(pf.s8, v1, O11, 0,0,0);
                }
            }
        }
    }

    // row sums: lane's rs covers q=l16, its quad's keys -> sum across quads
    float ls0 = rs0; ls0 += __shfl_xor(ls0, 16); ls0 += __shfl_xor(ls0, 32);
    float ls1 = rs1; ls1 += __shfl_xor(ls1, 16); ls1 += __shfl_xor(ls1, 32);
    // per-O-row l (rows are q = quad*4+i)
    float lrow[2][4];
#pragma unroll
    for (int i = 0; i < 4; i++) {
        lrow[0][i] = __shfl(ls0, quad*4 + i);
        lrow[1][i] = __shfl(ls1, quad*4 + i);
    }

    __syncthreads();    // vlds reads done before aliasing as combine buffer

    // combine key-halves through LDS: [qh][32 rows][34 floats] (col 32 = l)
    float* comb = reinterpret_cast<float*>(&vlds[0][0]) + qh*(32*34);
    if (kh == 1) {
#pragma unroll
        for (int s = 0; s < 2; s++)
#pragma unroll
            for (int i = 0; i < 4; i++) {
                int row = s*16 + quad*4 + i;
                comb[row*34 + l16]      = (s ? O10[i] : O00[i]);
                comb[row*34 + 16 + l16] = (s ? O11[i] : O01[i]);
                if (l16 == 0) comb[row*34 + 32] = lrow[s][i];
            }
    }
    __syncthreads();

    if (kh == 0) {
        float* ob = out + (size_t)X*NTOK*CDIM + h*DHEAD;
#pragma unroll
        for (int s = 0; s < 2; s++) {
#pragma unroll
            for (int i = 0; i < 4; i++) {
                int row = s*16 + quad*4 + i;
                float l = lrow[s][i] + comb[row*34 + 32];
                float inv = 1.0f / l;
                float a = ((s ? O10[i] : O00[i]) + comb[row*34 + l16])      * inv;
                float b = ((s ? O11[i] : O01[i]) + comb[row*34 + 16 + l16]) * inv;
                int orow = q0 + row;
                ob[orow*CDIM + l16]      = a;
                ob[orow*CDIM + 16 + l16] = b;
            }
        }
    }
}

extern "C" void kernel_launch(void* const* d_in, const int* in_sizes, int n_in,
                              void* d_out, int out_size, void* d_ws, size_t ws_size,
                              hipStream_t stream)
{
    const float* before = (const float*)d_in[0];
    const float* after  = (const float*)d_in[1];
    const float* W      = (const float*)d_in[2];
    const float* gamma  = (const float*)d_in[3];
    const float* beta   = (const float*)d_in[4];
    float* out          = (float*)d_out;
    unsigned short* ws  = (unsigned short*)d_ws;   // needs ~13.0 MB

    hipLaunchKernelGGL(wconv_kernel, dim3(96), dim3(256), 0, stream, W, ws);
    hipLaunchKernelGGL(qkv_ln_kernel, dim3(1024), dim3(256), 0, stream,
                       before, after, gamma, beta, ws);
    hipLaunchKernelGGL(attn_kernel, dim3(64, 8, 2), dim3(256), 0, stream, ws, out);
}

// Round 9
// 145.809 us; speedup vs baseline: 1.9012x; 1.0568x over previous
//
#include <hip/hip_runtime.h>

// Shapes: B=1, N=4096, C=256, H=8, d=32.
// ws layout (ushort elems):
//   Q[2][8][4096][32]          @ 0         (Q pre-scaled by d^-0.5*log2e)
//   K[2][8][4096][32]          @ KOFF
//   Vt[2][8][32][4096]         @ VOFF      (key dim permuted per 32-block to
//                                           PV A-frag slot order: ki<16 ->
//                                           (ki>>2)*8+(ki&3), else +4)
//   WBF[24][8192]              @ WOFF      (W bf16, swizzled to B-frag order)

typedef __attribute__((ext_vector_type(8))) short short8;
typedef __attribute__((ext_vector_type(4))) float float4v;
typedef __attribute__((ext_vector_type(4))) unsigned int uint4v;

#define NTOK 4096
#define CDIM 256
#define HEADS 8
#define DHEAD 32

#define QOFF 0
#define KOFF (2*HEADS*NTOK*DHEAD)
#define VOFF (2*(2*HEADS*NTOK*DHEAD))
#define WOFF (3*(2*HEADS*NTOK*DHEAD))

__device__ inline unsigned short f2bf(float f) {
    union { float f; unsigned u; } v; v.f = f;
    unsigned r = v.u + 0x7FFFu + ((v.u >> 16) & 1u);   // RNE
    return (unsigned short)(r >> 16);
}

// ---------------------------------------------------------------------------
// Kernel 0: W fp32 -> bf16, swizzled so a B-fragment is one contiguous 16B
// load: WBF[o32*8192 + (kk*2+nhalf)*512 + (quad*16+l16)*8 + j]
// ---------------------------------------------------------------------------
__global__ __launch_bounds__(256) void wconv_kernel(
    const float* __restrict__ W, unsigned short* __restrict__ ws)
{
    int idx = blockIdx.x*256 + threadIdx.x;    // [0, 24576): (row, col-octet)
    int R = idx >> 5, oct = idx & 31;
    int C = oct * 8;
    const float4* p = reinterpret_cast<const float4*>(W + R*CDIM + C);
    float4 a = p[0], b = p[1];
    short8 f;
    f[0]=(short)f2bf(a.x); f[1]=(short)f2bf(a.y); f[2]=(short)f2bf(a.z); f[3]=(short)f2bf(a.w);
    f[4]=(short)f2bf(b.x); f[5]=(short)f2bf(b.y); f[6]=(short)f2bf(b.z); f[7]=(short)f2bf(b.w);
    int o32 = R >> 5, r = R & 31;
    int kk = C >> 5, quad = (C >> 3) & 3;
    int dst = o32*8192 + (kk*2 + (r>>4))*512 + (quad*16 + (r&15))*8;
    *reinterpret_cast<short8*>(ws + WOFF + dst) = f;
}

// ---------------------------------------------------------------------------
// Kernel 1: t = x @ W^T (bf16 MFMA) + LayerNorm over d=32 groups.
// No LDS/barriers. grid = 1024: (row-tile 0..127) x (o-eighth 0..7, 3 o32s).
// ---------------------------------------------------------------------------
__global__ __launch_bounds__(256) void qkv_ln_kernel(
    const float* __restrict__ before, const float* __restrict__ after,
    const float* __restrict__ gamma, const float* __restrict__ beta,
    unsigned short* __restrict__ ws)
{
    const int tid  = threadIdx.x;
    const int lane = tid & 63;
    const int w    = tid >> 6;
    const int quad = lane >> 4;
    const int l16  = lane & 15;
    const int rt   = blockIdx.x >> 3;
    const int oq   = blockIdx.x & 7;

    const int mrow_frag = rt*64 + w*16 + l16;
    const int inp_f = mrow_frag >> 12;
    const int n_f   = mrow_frag & 4095;
    const float* x = inp_f ? after : before;

    short8 afrag[8];
#pragma unroll
    for (int kk = 0; kk < 8; kk++) {
        const float4* p = reinterpret_cast<const float4*>(x + n_f*CDIM + kk*32 + quad*8);
        float4 a = p[0], b = p[1];
        short8 f;
        f[0]=(short)f2bf(a.x); f[1]=(short)f2bf(a.y); f[2]=(short)f2bf(a.z); f[3]=(short)f2bf(a.w);
        f[4]=(short)f2bf(b.x); f[5]=(short)f2bf(b.y); f[6]=(short)f2bf(b.z); f[7]=(short)f2bf(b.w);
        afrag[kk] = f;
    }

    const float g0  = gamma[l16], g1  = gamma[16+l16];
    const float be0 = beta[l16],  be1 = beta[16+l16];
    const float cscale = 0.17677669529663687f * 1.4426950408889634f; // d^-0.5*log2e

    const int mrow_out  = rt*64 + w*16 + quad*4;
    const int inp_o     = mrow_out >> 12;
    const int n_o_base  = mrow_out & 4095;

    const unsigned short* wbf = ws + WOFF;

    for (int o32 = oq*3; o32 < oq*3 + 3; o32++) {
        const unsigned short* wb = wbf + o32*8192 + lane*8;
        float4v acc0 = {0.f,0.f,0.f,0.f}, acc1 = {0.f,0.f,0.f,0.f};
#pragma unroll
        for (int kk = 0; kk < 8; kk++) {
            short8 b0 = *reinterpret_cast<const short8*>(wb + (kk*2    )*512);
            short8 b1 = *reinterpret_cast<const short8*>(wb + (kk*2 + 1)*512);
            acc0 = __builtin_amdgcn_mfma_f32_16x16x32_bf16(afrag[kk], b0, acc0, 0,0,0);
            acc1 = __builtin_amdgcn_mfma_f32_16x16x32_bf16(afrag[kk], b1, acc1, 0,0,0);
        }

        const int which = o32 >> 3;     // 0=q 1=k 2=v
        const int h     = o32 & 7;
        unsigned short* qk = ws + (which == 0 ? QOFF : KOFF) + ((inp_o*HEADS + h)*NTOK)*DHEAD;
        unsigned short* vt = ws + VOFF + ((inp_o*HEADS + h)*DHEAD)*NTOK;
        const float qs = (which == 0) ? cscale : 1.0f;

#pragma unroll
        for (int i = 0; i < 4; i++) {
            float sum = acc0[i] + acc1[i];
            float sq  = acc0[i]*acc0[i] + acc1[i]*acc1[i];
#pragma unroll
            for (int m = 1; m < 16; m <<= 1) {
                sum += __shfl_xor(sum, m);
                sq  += __shfl_xor(sq,  m);
            }
            float mu   = sum * (1.0f/32.0f);
            float var  = sq * (1.0f/32.0f) - mu*mu;
            float rstd = rsqrtf(var + 1e-5f);
            float v0 = ((acc0[i]-mu)*rstd*g0 + be0) * qs;
            float v1 = ((acc1[i]-mu)*rstd*g1 + be1) * qs;
            int n = n_o_base + i;
            if (which < 2) {
                qk[n*DHEAD + l16]      = f2bf(v0);
                qk[n*DHEAD + 16 + l16] = f2bf(v1);
            } else {
                // PV A-frag slot order within each 32-key block
                int kb = n >> 5, ki = n & 31;
                int slot = ((ki & 15) >> 2)*8 + (ki & 3) + ((ki >> 4) << 2);
                int kp2 = kb*32 + slot;
                vt[l16*NTOK + kp2]       = f2bf(v0);
                vt[(16+l16)*NTOK + kp2]  = f2bf(v1);
            }
        }
    }
}

// ---------------------------------------------------------------------------
// Kernel 2: cross attention, max-free softmax, no P LDS round-trip (S^T via
// K·Q^T lands as the PV A-fragment), and row-sums l computed on the MFMA pipe
// via an extra PV MFMA against a ones B-fragment (same bf16 P as PV -> the
// P-rounding bias cancels exactly in O/l, so P is packed by truncation: no
// bias adds, no rsum adds, no end shuffles).
// Block = 4 waves = (q-half) x (key-half); V staged in LDS per key-half;
// key-halves merge O/l partials through LDS. grid (64,8,2) = 1024 blocks.
// ---------------------------------------------------------------------------
__global__ __launch_bounds__(256, 4) void attn_kernel(
    const unsigned short* __restrict__ ws, float* __restrict__ out)
{
    __shared__ unsigned short vlds[2][32*136];   // per key-half: 32 d x 128 k'

    const int X  = blockIdx.z;
    const int h  = blockIdx.y;
    const int qb = blockIdx.x;                  // 64 q-rows per block
    const int qinp = 1 - X, kvinp = X;
    const int tid  = threadIdx.x;
    const int lane = tid & 63;
    const int w    = tid >> 6;
    const int qh   = w & 1;                     // q-half
    const int kh   = w >> 1;                    // key-half
    const int quad = lane >> 4;
    const int l16  = lane & 15;

    const unsigned short* qbase = ws + QOFF + ((qinp*HEADS + h)*NTOK)*DHEAD;
    const unsigned short* kbase = ws + KOFF + ((kvinp*HEADS + h)*NTOK)*DHEAD;
    const unsigned short* vbase = ws + VOFF + ((kvinp*HEADS + h)*DHEAD)*NTOK;

    const int q0 = qb*64 + qh*32;
    // Q as B-operand: B[n=q=l16][k=d=quad*8+j]
    const short8 qf0 = *reinterpret_cast<const short8*>(qbase + (q0 + l16)*DHEAD      + quad*8);
    const short8 qf1 = *reinterpret_cast<const short8*>(qbase + (q0 + 16 + l16)*DHEAD + quad*8);

    // K as A-operand: A[m=key(within tile)=l16][k=d=quad*8+j]
    const unsigned short* kp   = kbase + (kh*2048 + l16)*DHEAD + quad*8;
    const unsigned short* vsrc = vbase + kh*2048;   // rows stride NTOK

    const short8 ones = {0x3F80,0x3F80,0x3F80,0x3F80,0x3F80,0x3F80,0x3F80,0x3F80};

    float4v O00 = {0,0,0,0}, O01 = {0,0,0,0}, O10 = {0,0,0,0}, O11 = {0,0,0,0};
    float4v L0  = {0,0,0,0}, L1  = {0,0,0,0};   // row-sum accumulators

    unsigned short* vh = vlds[kh];
    const int t2 = qh*64 + lane;                // 0..127 within the kh pair

    for (int j = 0; j < 16; j++) {
        __syncthreads();    // prior PV reads of vlds complete
        // stage vlds[kh]: 32 d-rows x 128 k' cols; 128 threads x 4 stores
#pragma unroll
        for (int r = 0; r < 4; r++) {
            int c = t2 + 128*r;                 // 0..511
            short8 d = *reinterpret_cast<const short8*>(vsrc + (c>>4)*NTOK + j*128 + (c&15)*8);
            *reinterpret_cast<short8*>(vh + (c>>4)*136 + (c&15)*8) = d;
        }
        __syncthreads();

#pragma unroll
        for (int grp = 0; grp < 4; grp++) {     // 32-key groups
            short8 kf0 = *reinterpret_cast<const short8*>(kp + (j*128 + grp*32     )*DHEAD);
            short8 kf1 = *reinterpret_cast<const short8*>(kp + (j*128 + grp*32 + 16)*DHEAD);
            short8 v0  = *reinterpret_cast<const short8*>(vh + l16*136      + grp*32 + quad*8);
            short8 v1  = *reinterpret_cast<const short8*>(vh + (16+l16)*136 + grp*32 + quad*8);
#pragma unroll
            for (int s = 0; s < 2; s++) {
                const short8 qf = s ? qf1 : qf0;
                float4v z = {0,0,0,0};
                float4v S0 = __builtin_amdgcn_mfma_f32_16x16x32_bf16(kf0, qf, z, 0,0,0);
                float4v S1 = __builtin_amdgcn_mfma_f32_16x16x32_bf16(kf1, qf, z, 0,0,0);
                union { float f; unsigned u; } u0,u1,u2,u3,u4,u5,u6,u7;
                u0.f = __builtin_amdgcn_exp2f(S0[0]);
                u1.f = __builtin_amdgcn_exp2f(S0[1]);
                u2.f = __builtin_amdgcn_exp2f(S0[2]);
                u3.f = __builtin_amdgcn_exp2f(S0[3]);
                u4.f = __builtin_amdgcn_exp2f(S1[0]);
                u5.f = __builtin_amdgcn_exp2f(S1[1]);
                u6.f = __builtin_amdgcn_exp2f(S1[2]);
                u7.f = __builtin_amdgcn_exp2f(S1[3]);
                union { short8 s8; uint4v u4v; } pf;     // truncation pack
                pf.u4v[0] = __builtin_amdgcn_perm(u1.u, u0.u, 0x07060302u);
                pf.u4v[1] = __builtin_amdgcn_perm(u3.u, u2.u, 0x07060302u);
                pf.u4v[2] = __builtin_amdgcn_perm(u5.u, u4.u, 0x07060302u);
                pf.u4v[3] = __builtin_amdgcn_perm(u7.u, u6.u, 0x07060302u);
                if (s == 0) {
                    O00 = __builtin_amdgcn_mfma_f32_16x16x32_bf16(pf.s8, v0,   O00, 0,0,0);
                    O01 = __builtin_amdgcn_mfma_f32_16x16x32_bf16(pf.s8, v1,   O01, 0,0,0);
                    L0  = __builtin_amdgcn_mfma_f32_16x16x32_bf16(pf.s8, ones, L0,  0,0,0);
                } else {
                    O10 = __builtin_amdgcn_mfma_f32_16x16x32_bf16(pf.s8, v0,   O10, 0,0,0);
                    O11 = __builtin_amdgcn_mfma_f32_16x16x32_bf16(pf.s8, v1,   O11, 0,0,0);
                    L1  = __builtin_amdgcn_mfma_f32_16x16x32_bf16(pf.s8, ones, L1,  0,0,0);
                }
            }
        }
    }

    __syncthreads();    // vlds reads done before aliasing as combine buffer

    // combine key-halves through LDS: [qh][32 rows][34 floats] (col 32 = l)
    // L accumulators: row = q (quad*4+i), all cols equal -> lane's L[i] is l.
    float* comb = reinterpret_cast<float*>(&vlds[0][0]) + qh*(32*34);
    if (kh == 1) {
#pragma unroll
        for (int s = 0; s < 2; s++)
#pragma unroll
            for (int i = 0; i < 4; i++) {
                int row = s*16 + quad*4 + i;
                comb[row*34 + l16]      = (s ? O10[i] : O00[i]);
                comb[row*34 + 16 + l16] = (s ? O11[i] : O01[i]);
                if (l16 == 0) comb[row*34 + 32] = (s ? L1[i] : L0[i]);
            }
    }
    __syncthreads();

    if (kh == 0) {
        float* ob = out + (size_t)X*NTOK*CDIM + h*DHEAD;
#pragma unroll
        for (int s = 0; s < 2; s++) {
#pragma unroll
            for (int i = 0; i < 4; i++) {
                int row = s*16 + quad*4 + i;
                float l = (s ? L1[i] : L0[i]) + comb[row*34 + 32];
                float inv = 1.0f / l;
                float a = ((s ? O10[i] : O00[i]) + comb[row*34 + l16])      * inv;
                float b = ((s ? O11[i] : O01[i]) + comb[row*34 + 16 + l16]) * inv;
                int orow = q0 + row;
                ob[orow*CDIM + l16]      = a;
                ob[orow*CDIM + 16 + l16] = b;
            }
        }
    }
}

extern "C" void kernel_launch(void* const* d_in, const int* in_sizes, int n_in,
                              void* d_out, int out_size, void* d_ws, size_t ws_size,
                              hipStream_t stream)
{
    const float* before = (const float*)d_in[0];
    const float* after  = (const float*)d_in[1];
    const float* W      = (const float*)d_in[2];
    const float* gamma  = (const float*)d_in[3];
    const float* beta   = (const float*)d_in[4];
    float* out          = (float*)d_out;
    unsigned short* ws  = (unsigned short*)d_ws;   // needs ~13.0 MB

    hipLaunchKernelGGL(wconv_kernel, dim3(96), dim3(256), 0, stream, W, ws);
    hipLaunchKernelGGL(qkv_ln_kernel, dim3(1024), dim3(256), 0, stream,
                       before, after, gamma, beta, ws);
    hipLaunchKernelGGL(attn_kernel, dim3(64, 8, 2), dim3(256), 0, stream, ws, out);
}